// Round 11
// baseline (238.092 us; speedup 1.0000x reference)
//
#include <hip/hip_runtime.h>
#include <hip/hip_fp16.h>
#include <math.h>

#define BB 16
#define SS 256
#define CC 17
#define NCH 16
#define DD 32
#define DFFN 64
#define HH 4
#define DH 8
#define EE 4

// ws layout (4-byte units):
//  [16 ..143]  K0[e][d]   [144..271] V0[e][d]
//  [512..66047]  XNS[b][s][n]
//  ints at WS_SPI: SP[b][p] (4096), OFF[b][e] (64)
//  WS_WT: weight images (16384 uints): WqT/WkT/WvT 6144 | WoT 2048 | W1T 4096 | W2T 2x2048
#define WS_K0 16
#define WS_V0 144
#define WS_XNS 512
#define WS_SPI (WS_XNS + BB*SS*NCH)          // 66048
#define WS_WT  (WS_SPI + BB*SS + 64)         // 70208
#define WS_WL  (WS_WT + 6144)

#define PRE 0.51006977f   // (1/sqrt(8)) * log2(e)

typedef __fp16 hv2 __attribute__((ext_vector_type(2)));

__device__ __forceinline__ unsigned pkh2(float a, float b) {
  hv2 r = __builtin_amdgcn_cvt_pkrtz(a, b);
  unsigned u; __builtin_memcpy(&u, &r, 4);
  return u;
}
__device__ __forceinline__ float fd2(unsigned a, unsigned b, float c) {
  hv2 av, bv;
  __builtin_memcpy(&av, &a, 4);
  __builtin_memcpy(&bv, &b, 4);
  return __builtin_amdgcn_fdot2(av, bv, c, false);
}
__device__ __forceinline__ __half2 u2h2(unsigned u) {
  __half2 h; __builtin_memcpy(&h, &u, 4); return h;
}
template<int PAT>
__device__ __forceinline__ unsigned qdpp(unsigned v) {
  return (unsigned)__builtin_amdgcn_mov_dpp((int)v, PAT, 0xF, 0xF, true);
}
template<int PAT>
__device__ __forceinline__ float qdppf(float v) {
  return __uint_as_float(qdpp<PAT>(__float_as_uint(v)));
}

// ---------------------------------------------------------------------------
// Kernel 1 (1024 thr): decomp (blocks 0..255), prep (256..271),
// weight-image convert (272..275). [unchanged from R10]
// ---------------------------------------------------------------------------
__launch_bounds__(1024)
__global__ void decomp_prep_kernel(const float* __restrict__ x,
                                   const float* __restrict__ ox,
                                   const float* __restrict__ sb,
                                   const float* __restrict__ g1,
                                   const float* __restrict__ bb1,
                                   const float* __restrict__ Wq,
                                   const float* __restrict__ Wk,
                                   const float* __restrict__ Wv,
                                   const float* __restrict__ Wo,
                                   const float* __restrict__ W1,
                                   const float* __restrict__ W2,
                                   float* __restrict__ ws) {
  const int t = threadIdx.x;  // 1024
  if (blockIdx.x < 256) {
    const int b = blockIdx.x / NCH;
    const int c = blockIdx.x % NCH;
    __shared__ float xs[SS];
    __shared__ float prr[1024], pii[1024];
    __shared__ float amp[129];
    __shared__ float2 YY[129];
    __shared__ float sth;
    if (t < SS) xs[t] = x[(b*SS + t)*CC + c];
    __syncthreads();
    const float TH0 = 0.024543692606170259f;  // 2*pi/256
    {
      const int f = (t & 127) + 1;
      const int chunk = t >> 7;
      const int s0 = chunk * 32;
      const int ph0 = (f * s0) & 255;
      float si, cr; sincosf(TH0*(float)ph0, &si, &cr);
      float s1, c1; sincosf(TH0*(float)f, &s1, &c1);
      float xr = 0.f, xi = 0.f;
      #pragma unroll 4
      for (int k = 0; k < 32; ++k) {
        float xvv = xs[s0 + k];
        xr += xvv * cr;
        xi -= xvv * si;
        float nc = cr*c1 - si*s1;
        si = si*c1 + cr*s1;
        cr = nc;
      }
      prr[t] = xr; pii[t] = xi;
    }
    __syncthreads();
    if (t < 128) {
      float xr = 0.f, xi = 0.f;
      #pragma unroll
      for (int k2 = 0; k2 < 8; ++k2) { xr += prr[t + 128*k2]; xi += pii[t + 128*k2]; }
      prr[t] = xr; pii[t] = xi;
      amp[t+1] = sqrtf(xr*xr + xi*xi);
    }
    __syncthreads();
    if (t < 64) {
      float a0 = amp[t+1], a1 = amp[t+65];
      int i0 = t+1, i1 = t+65;
      float th = -1e30f;
      for (int r = 0; r < 4; ++r) {
        float mv = (a0 > a1) ? a0 : a1;
        int   mi = (a0 > a1) ? i0 : i1;
        for (int off = 32; off > 0; off >>= 1) {
          float ov = __shfl_xor(mv, off);
          int   oi = __shfl_xor(mi, off);
          if (ov > mv || (ov == mv && oi < mi)) { mv = ov; mi = oi; }
        }
        th = mv;
        if (mi == i0) a0 = -1e30f;
        if (mi == i1) a1 = -1e30f;
      }
      if (t == 0) sth = th;
    }
    __syncthreads();
    if (t < 128) {
      const int f = t + 1;
      float wgt = (amp[f] >= sth) ? ((f == 128) ? 1.0f : 2.0f) * (1.0f/256.0f) : 0.0f;
      YY[f] = make_float2(wgt * prr[t], wgt * pii[t]);
    }
    __syncthreads();
    {
      const int s = t & 255;
      const int fc = t >> 8;
      const int f0 = 1 + fc*32;
      const int ph0 = (s * f0) & 255;
      float si, cr; sincosf(TH0*(float)ph0, &si, &cr);
      float s1, c1; sincosf(TH0*(float)s, &s1, &c1);
      float acc = 0.f;
      #pragma unroll 4
      for (int k = 0; k < 32; ++k) {
        float2 y = YY[f0 + k];
        acc += y.x*cr - y.y*si;
        float nc = cr*c1 - si*s1;
        si = si*c1 + cr*s1;
        cr = nc;
      }
      prr[t] = acc;
    }
    __syncthreads();
    if (t < 256) {
      float season = prr[t] + prr[t+256] + prr[t+512] + prr[t+768];
      float s4 = 0.f, s8 = 0.f, s12 = 0.f;
      #pragma unroll
      for (int j = 0; j < 4; ++j)  { int p = t + j - 1; p = p < 0 ? 0 : (p > SS-1 ? SS-1 : p); s4  += xs[p]; }
      #pragma unroll
      for (int j = 0; j < 8; ++j)  { int p = t + j - 3; p = p < 0 ? 0 : (p > SS-1 ? SS-1 : p); s8  += xs[p]; }
      #pragma unroll
      for (int j = 0; j < 12; ++j) { int p = t + j - 5; p = p < 0 ? 0 : (p > SS-1 ? SS-1 : p); s12 += xs[p]; }
      float trend = (s4 * 0.25f + s8 * 0.125f + s12 * (1.0f/12.0f)) * (1.0f/3.0f);
      ws[WS_XNS + (b*SS + t)*NCH + c] = xs[t] + season + trend;
    }
  } else if (blockIdx.x < 272) {
    const int b = blockIdx.x - 256;
    __shared__ float red[32];
    __shared__ int asg[SS];
    __shared__ int cnt[EE];
    __shared__ float z0[EE*DD];
    float mn = 3e38f, mx = -3e38f;
    #pragma unroll
    for (int k = 0; k < 4; ++k) {
      float v = ox[(t + k*1024)*2 + 1];
      mn = fminf(mn, v); mx = fmaxf(mx, v);
    }
    for (int off = 32; off > 0; off >>= 1) {
      mn = fminf(mn, __shfl_xor(mn, off));
      mx = fmaxf(mx, __shfl_xor(mx, off));
    }
    if ((t & 63) == 0) { red[(t>>6)*2] = mn; red[(t>>6)*2+1] = mx; }
    __syncthreads();
    mn = red[0]; mx = red[1];
    #pragma unroll
    for (int w = 1; w < 16; ++w) { mn = fminf(mn, red[w*2]); mx = fmaxf(mx, red[w*2+1]); }
    const float step = (mx - mn) * 0.25f;
    const float e1 = mn + step, e2 = mn + 2.f*step, e3 = mn + 3.f*step;
    if (t < 256) {
      float sc = ox[(b*SS + t)*2 + 1];
      asg[t] = (sc >= e1) + (sc >= e2) + (sc >= e3);
    }
    __syncthreads();
    if (t < EE) {
      int c = 0;
      for (int s2 = 0; s2 < SS; ++s2) c += (asg[s2] == t);
      cnt[t] = c;
    }
    __syncthreads();
    int* SPw  = (int*)ws + WS_SPI;
    int* OFFw = SPw + BB*SS;
    if (t < EE) {
      int off = 0;
      for (int i = 0; i < t; ++i) off += cnt[i];
      OFFw[b*EE + t] = off;
      int kp = off;
      for (int s2 = 0; s2 < SS; ++s2) if (asg[s2] == t) SPw[b*SS + (kp++)] = s2;
    }
    if (t < 128) {
      int ee = t >> 5, d = t & 31;
      float m = 0.f;
      for (int i = 0; i < DD; ++i) m += sb[i];
      m *= (1.0f/DD);
      float var = 0.f;
      for (int i = 0; i < DD; ++i) { float df = sb[i]-m; var += df*df; }
      var *= (1.0f/DD);
      float rs = rsqrtf(var + 1e-5f);
      z0[ee*DD + d] = (sb[d]-m)*rs*g1[ee*DD+d] + bb1[ee*DD+d];
    }
    __syncthreads();
    if (b == 0 && t < 128) {
      int ee = t >> 5, d = t & 31;
      float k0 = 0.f, v0 = 0.f;
      for (int i = 0; i < DD; ++i) {
        float zz = z0[ee*DD + i];
        k0 += zz * Wk[ee*DD*DD + i*DD + d];
        v0 += zz * Wv[ee*DD*DD + i*DD + d];
      }
      ws[WS_K0 + ee*DD + d] = k0;
      ws[WS_V0 + ee*DD + d] = v0;
    }
  } else {
    unsigned* img = (unsigned*)ws + WS_WT;
    const int base_u = (blockIdx.x - 272)*4096;
    #pragma unroll
    for (int i = 0; i < 4; ++i) {
      int u = base_u + i*1024 + t;
      unsigned val;
      if (u < 6144) {                    // Wq/Wk/Wv T
        int mat = u >> 11, r = u & 2047;
        int row = r >> 4, ip = r & 15;
        int e = row >> 5, q = row & 31;
        int d = (q & 3)*8 + (q >> 2);
        const float* Wm = (mat == 0) ? Wq : (mat == 1) ? Wk : Wv;
        const float* src = Wm + e*1024 + d;
        val = pkh2(src[ip*64], src[ip*64 + 32]);
      } else {
        int v = u - 6144;
        if (v < 2048) {                  // WoT
          int row = v >> 4, ip = v & 15;
          int e = row >> 5, q = row & 31;
          int d = (q & 3)*8 + (q >> 2);
          const float* src = Wo + e*1024 + d;
          val = pkh2(src[ip*64], src[ip*64 + 32]);
        } else if (v < 6144) {           // W1T
          int r = v - 2048;
          int row = r >> 4, ip = r & 15;
          int e = row >> 6, q = row & 63;
          int j = (q & 3)*16 + (q >> 2);
          const float* src = W1 + e*2048 + j;
          val = pkh2(src[ip*128], src[ip*128 + 64]);
        } else {                         // W2T (two planes)
          int r = v - 6144;
          int a = r >> 11, rr = r & 2047;
          int row = rr >> 4, ip = rr & 15;
          int e = row >> 5, q = row & 31;
          int d = (q & 3)*8 + (q >> 2);
          int jp = a*16 + ip;
          const float* src = W2 + e*2048 + d;
          val = pkh2(src[2*jp*32], src[(2*jp+1)*32]);
        }
      }
      img[u] = val;
    }
  }
}

// ---------------------------------------------------------------------------
// Kernel 2: fused, 2 positions per thread. Grid (b,n)=256 x 512 thr (8 waves).
// Thread = (pp, hh) owns sorted positions 2pp, 2pp+1 (same expert except at
// <=3 boundary quads -> rare reload branch). Attention iterates the union
// segment once: k/v reads serve both positions. 2 barriers; DPP exchanges.
// ---------------------------------------------------------------------------
__launch_bounds__(512, 2)
__global__ void fused_kernel(const float* __restrict__ ws,
    const float* __restrict__ g1, const float* __restrict__ bb1,
    const float* __restrict__ sW, const float* __restrict__ sb,
    const float* __restrict__ g2, const float* __restrict__ bb2,
    const float* __restrict__ b1, const float* __restrict__ b2,
    float* __restrict__ out) {
  const int blk = blockIdx.x;
  const int n = blk & 15;
  const int b = blk >> 4;
  const int t = threadIdx.x;      // 0..511
  const int pp = t >> 2;          // 0..127
  const int hh = t & 3;
  const int p0 = pp*2, p1 = pp*2 + 1;
  __shared__ unsigned lds[24576];
  unsigned* wT = lds + 8192;
  unsigned* wl = lds + 14336;

  // async-stage weight images (16384 uints = 64 x 1KB chunks, 8/wave)
  {
    const unsigned* img = (const unsigned*)ws + WS_WT;
    const int wv = t >> 6;
    const int ln = t & 63;
    #pragma unroll
    for (int i = 0; i < 8; ++i) {
      const int ch = wv*8 + i;
      __builtin_amdgcn_global_load_lds(
          (const __attribute__((address_space(1))) unsigned*)(img + ch*256 + ln*4),
          (__attribute__((address_space(3))) unsigned*)(wT + ch*256 + ln*4),
          16, 0, 0);
    }
  }

  const int* SP  = (const int*)ws + WS_SPI;
  const int* OFF = SP + BB*SS;
  const int o1 = OFF[b*4+1], o2v = OFF[b*4+2], o3 = OFF[b*4+3];
  const int e0 = (p0 >= o1) + (p0 >= o2v) + (p0 >= o3);
  const int e1 = (p1 >= o1) + (p1 >= o2v) + (p1 >= o3);
  const bool same_e = (e0 == e1);
  const int beg0 = (e0==0) ? 0  : ((e0==1) ? o1 : ((e0==2) ? o2v : o3));
  const int end0 = (e0==0) ? o1 : ((e0==1) ? o2v : ((e0==2) ? o3 : SS));
  const int beg1 = (e1==0) ? 0  : ((e1==1) ? o1 : ((e1==2) ? o2v : o3));
  const int end1 = (e1==0) ? o1 : ((e1==1) ? o2v : ((e1==2) ? o3 : SS));
  const int sA = SP[b*SS + p0];
  const int sB = SP[b*SS + p1];
  const float xv0 = ws[WS_XNS + (b*SS + sA)*NCH + n];
  const float xv1 = ws[WS_XNS + (b*SS + sB)*NCH + n];

  // LN1 for both positions
  unsigned zp0[16], zp1[16];
  {
    float h[DD];
    #pragma unroll
    for (int d = 0; d < DD; ++d) h[d] = xv0 * sW[d] + sb[d];
    float m = 0.f;
    #pragma unroll
    for (int d = 0; d < DD; ++d) m += h[d];
    m *= (1.0f/DD);
    float var = 0.f;
    #pragma unroll
    for (int d = 0; d < DD; ++d) { float df = h[d]-m; var += df*df; }
    float rs = rsqrtf(var*(1.0f/DD) + 1e-5f);
    #pragma unroll
    for (int ip = 0; ip < 16; ++ip) {
      float za = (h[2*ip]  -m)*rs*g1[e0*DD+2*ip]   + bb1[e0*DD+2*ip];
      float zb = (h[2*ip+1]-m)*rs*g1[e0*DD+2*ip+1] + bb1[e0*DD+2*ip+1];
      zp0[ip] = pkh2(za, zb);
    }
  }
  {
    float h[DD];
    #pragma unroll
    for (int d = 0; d < DD; ++d) h[d] = xv1 * sW[d] + sb[d];
    float m = 0.f;
    #pragma unroll
    for (int d = 0; d < DD; ++d) m += h[d];
    m *= (1.0f/DD);
    float var = 0.f;
    #pragma unroll
    for (int d = 0; d < DD; ++d) { float df = h[d]-m; var += df*df; }
    float rs = rsqrtf(var*(1.0f/DD) + 1e-5f);
    #pragma unroll
    for (int ip = 0; ip < 16; ++ip) {
      float za = (h[2*ip]  -m)*rs*g1[e1*DD+2*ip]   + bb1[e1*DD+2*ip];
      float zb = (h[2*ip+1]-m)*rs*g1[e1*DD+2*ip+1] + bb1[e1*DD+2*ip+1];
      zp1[ip] = pkh2(za, zb);
    }
  }
  __syncthreads();   // barrier 1: weight images staged

  // qkv for both positions; weight rows shared when same_e
  float q0[DH], q1[DH], kk0[DH], kk1[DH], vv0[DH], vv1[DH];
  #pragma unroll
  for (int dd = 0; dd < DH; ++dd) {
    const int r0 = (e0*32 + dd*4 + hh)*16;
    const uint4* rq = (const uint4*)&wT[r0];
    const uint4* rk = (const uint4*)&wT[2048 + r0];
    const uint4* rv = (const uint4*)&wT[4096 + r0];
    float aq0=0.f, ak0=0.f, av0=0.f, aq1=0.f, ak1=0.f, av1=0.f;
    #pragma unroll
    for (int g4 = 0; g4 < 4; ++g4) {
      uint4 wq4 = rq[g4], wk4 = rk[g4], wv4 = rv[g4];
      aq0 = fd2(zp0[4*g4+0], wq4.x, aq0); aq0 = fd2(zp0[4*g4+1], wq4.y, aq0);
      aq0 = fd2(zp0[4*g4+2], wq4.z, aq0); aq0 = fd2(zp0[4*g4+3], wq4.w, aq0);
      ak0 = fd2(zp0[4*g4+0], wk4.x, ak0); ak0 = fd2(zp0[4*g4+1], wk4.y, ak0);
      ak0 = fd2(zp0[4*g4+2], wk4.z, ak0); ak0 = fd2(zp0[4*g4+3], wk4.w, ak0);
      av0 = fd2(zp0[4*g4+0], wv4.x, av0); av0 = fd2(zp0[4*g4+1], wv4.y, av0);
      av0 = fd2(zp0[4*g4+2], wv4.z, av0); av0 = fd2(zp0[4*g4+3], wv4.w, av0);
      if (same_e) {
        aq1 = fd2(zp1[4*g4+0], wq4.x, aq1); aq1 = fd2(zp1[4*g4+1], wq4.y, aq1);
        aq1 = fd2(zp1[4*g4+2], wq4.z, aq1); aq1 = fd2(zp1[4*g4+3], wq4.w, aq1);
        ak1 = fd2(zp1[4*g4+0], wk4.x, ak1); ak1 = fd2(zp1[4*g4+1], wk4.y, ak1);
        ak1 = fd2(zp1[4*g4+2], wk4.z, ak1); ak1 = fd2(zp1[4*g4+3], wk4.w, ak1);
        av1 = fd2(zp1[4*g4+0], wv4.x, av1); av1 = fd2(zp1[4*g4+1], wv4.y, av1);
        av1 = fd2(zp1[4*g4+2], wv4.z, av1); av1 = fd2(zp1[4*g4+3], wv4.w, av1);
      }
    }
    if (!same_e) {
      const int r1 = (e1*32 + dd*4 + hh)*16;
      const uint4* rq1p = (const uint4*)&wT[r1];
      const uint4* rk1p = (const uint4*)&wT[2048 + r1];
      const uint4* rv1p = (const uint4*)&wT[4096 + r1];
      #pragma unroll
      for (int g4 = 0; g4 < 4; ++g4) {
        uint4 wq4 = rq1p[g4], wk4 = rk1p[g4], wv4 = rv1p[g4];
        aq1 = fd2(zp1[4*g4+0], wq4.x, aq1); aq1 = fd2(zp1[4*g4+1], wq4.y, aq1);
        aq1 = fd2(zp1[4*g4+2], wq4.z, aq1); aq1 = fd2(zp1[4*g4+3], wq4.w, aq1);
        ak1 = fd2(zp1[4*g4+0], wk4.x, ak1); ak1 = fd2(zp1[4*g4+1], wk4.y, ak1);
        ak1 = fd2(zp1[4*g4+2], wk4.z, ak1); ak1 = fd2(zp1[4*g4+3], wk4.w, ak1);
        av1 = fd2(zp1[4*g4+0], wv4.x, av1); av1 = fd2(zp1[4*g4+1], wv4.y, av1);
        av1 = fd2(zp1[4*g4+2], wv4.z, av1); av1 = fd2(zp1[4*g4+3], wv4.w, av1);
      }
    }
    q0[dd] = aq0 * PRE; kk0[dd] = ak0; vv0[dd] = av0;
    q1[dd] = aq1 * PRE; kk1[dd] = ak1; vv1[dd] = av1;
  }
  // write k/v for both positions
  *(uint4*)&lds[p0*32 + hh*8]     = make_uint4(pkh2(kk0[0],kk0[1]), pkh2(kk0[2],kk0[3]),
                                               pkh2(kk0[4],kk0[5]), pkh2(kk0[6],kk0[7]));
  *(uint4*)&lds[p0*32 + hh*8 + 4] = make_uint4(pkh2(vv0[0],vv0[1]), pkh2(vv0[2],vv0[3]),
                                               pkh2(vv0[4],vv0[5]), pkh2(vv0[6],vv0[7]));
  *(uint4*)&lds[p1*32 + hh*8]     = make_uint4(pkh2(kk1[0],kk1[1]), pkh2(kk1[2],kk1[3]),
                                               pkh2(kk1[4],kk1[5]), pkh2(kk1[6],kk1[7]));
  *(uint4*)&lds[p1*32 + hh*8 + 4] = make_uint4(pkh2(vv1[0],vv1[1]), pkh2(vv1[2],vv1[3]),
                                               pkh2(vv1[4],vv1[5]), pkh2(vv1[6],vv1[7]));
  unsigned qp20[4], qp21[4];
  #pragma unroll
  for (int i = 0; i < 4; ++i) {
    qp20[i] = pkh2(q0[2*i], q0[2*i+1]);
    qp21[i] = pkh2(q1[2*i], q1[2*i+1]);
  }
  float sc0 = 0.f, sc1 = 0.f;
  #pragma unroll
  for (int d = 0; d < DH; ++d) {
    sc0 += q0[d] * ws[WS_K0 + e0*DD + hh*DH + d];
    sc1 += q1[d] * ws[WS_K0 + e1*DD + hh*DH + d];
  }
  __syncthreads();   // barrier 2: kv staged — LAST barrier

  // attention over the union segment [beg0, end1): k/v read once, used twice
  float wsum0 = 0.f, wsum1 = 0.f;
  __half2 oa[4], ob[4];
  #pragma unroll
  for (int i = 0; i < 4; ++i) { oa[i] = u2h2(0u); ob[i] = u2h2(0u); }
  for (int j = beg0; j < end1; ++j) {
    uint4 ku = *(const uint4*)&lds[j*32 + hh*8];
    uint4 vu = *(const uint4*)&lds[j*32 + hh*8 + 4];
    float a0 = 0.f, a1 = 0.f;
    a0 = fd2(qp20[0], ku.x, a0); a0 = fd2(qp20[1], ku.y, a0);
    a0 = fd2(qp20[2], ku.z, a0); a0 = fd2(qp20[3], ku.w, a0);
    a1 = fd2(qp21[0], ku.x, a1); a1 = fd2(qp21[1], ku.y, a1);
    a1 = fd2(qp21[2], ku.z, a1); a1 = fd2(qp21[3], ku.w, a1);
    float w0k = (j < end0)  ? __builtin_amdgcn_exp2f(a0) : 0.f;
    float w1k = (j >= beg1) ? __builtin_amdgcn_exp2f(a1) : 0.f;
    wsum0 += w0k; wsum1 += w1k;
    __half2 w20 = u2h2(pkh2(w0k, w0k));
    __half2 w21 = u2h2(pkh2(w1k, w1k));
    oa[0] = __hfma2(w20, u2h2(vu.x), oa[0]);
    oa[1] = __hfma2(w20, u2h2(vu.y), oa[1]);
    oa[2] = __hfma2(w20, u2h2(vu.z), oa[2]);
    oa[3] = __hfma2(w20, u2h2(vu.w), oa[3]);
    ob[0] = __hfma2(w21, u2h2(vu.x), ob[0]);
    ob[1] = __hfma2(w21, u2h2(vu.y), ob[1]);
    ob[2] = __hfma2(w21, u2h2(vu.z), ob[2]);
    ob[3] = __hfma2(w21, u2h2(vu.w), ob[3]);
  }
  float o0[DH], o1v[DH];
  #pragma unroll
  for (int i = 0; i < 4; ++i) {
    o0[2*i]   = __low2float(oa[i]);  o0[2*i+1]  = __high2float(oa[i]);
    o1v[2*i]  = __low2float(ob[i]);  o1v[2*i+1] = __high2float(ob[i]);
  }
  {
    const int nm0 = SS - (end0 - beg0);
    const int nm1 = SS - (end1 - beg1);
    float w00 = (float)nm0 * __builtin_amdgcn_exp2f(sc0);
    float w01 = (float)nm1 * __builtin_amdgcn_exp2f(sc1);
    wsum0 += w00; wsum1 += w01;
    #pragma unroll
    for (int d = 0; d < DH; ++d) {
      o0[d]  += w00 * ws[WS_V0 + e0*DD + hh*DH + d];
      o1v[d] += w01 * ws[WS_V0 + e1*DD + hh*DH + d];
    }
    float i0 = 1.0f / wsum0, i1 = 1.0f / wsum1;
    #pragma unroll
    for (int d = 0; d < DH; ++d) { o0[d] *= i0; o1v[d] *= i1; }
  }

  // o gather via DPP quad broadcast (quad = same pp)
  unsigned ovp0[16], ovp1[16];
  {
    unsigned oqa[4], oqb[4];
    #pragma unroll
    for (int j = 0; j < 4; ++j) {
      oqa[j] = pkh2(o0[2*j], o0[2*j+1]);
      oqb[j] = pkh2(o1v[2*j], o1v[2*j+1]);
    }
    #pragma unroll
    for (int j = 0; j < 4; ++j) {
      ovp0[j]    = qdpp<0x00>(oqa[j]);  ovp1[j]    = qdpp<0x00>(oqb[j]);
      ovp0[4+j]  = qdpp<0x55>(oqa[j]);  ovp1[4+j]  = qdpp<0x55>(oqb[j]);
      ovp0[8+j]  = qdpp<0xAA>(oqa[j]);  ovp1[8+j]  = qdpp<0xAA>(oqb[j]);
      ovp0[12+j] = qdpp<0xFF>(oqa[j]);  ovp1[12+j] = qdpp<0xFF>(oqb[j]);
    }
  }

  // Wo + residual
  float acc0[DH], acc1[DH];
  #pragma unroll
  for (int dd = 0; dd < DH; ++dd) {
    const int d = hh*DH + dd;
    const uint4* row0 = (const uint4*)&wl[(e0*32 + dd*4 + hh)*16];
    float a0 = xv0 * sW[d] + sb[d];
    float a1 = xv1 * sW[d] + sb[d];
    #pragma unroll
    for (int g4 = 0; g4 < 4; ++g4) {
      uint4 w4 = row0[g4];
      a0 = fd2(ovp0[4*g4+0], w4.x, a0); a0 = fd2(ovp0[4*g4+1], w4.y, a0);
      a0 = fd2(ovp0[4*g4+2], w4.z, a0); a0 = fd2(ovp0[4*g4+3], w4.w, a0);
      if (same_e) {
        a1 = fd2(ovp1[4*g4+0], w4.x, a1); a1 = fd2(ovp1[4*g4+1], w4.y, a1);
        a1 = fd2(ovp1[4*g4+2], w4.z, a1); a1 = fd2(ovp1[4*g4+3], w4.w, a1);
      }
    }
    if (!same_e) {
      const uint4* row1 = (const uint4*)&wl[(e1*32 + dd*4 + hh)*16];
      #pragma unroll
      for (int g4 = 0; g4 < 4; ++g4) {
        uint4 w4 = row1[g4];
        a1 = fd2(ovp1[4*g4+0], w4.x, a1); a1 = fd2(ovp1[4*g4+1], w4.y, a1);
        a1 = fd2(ovp1[4*g4+2], w4.z, a1); a1 = fd2(ovp1[4*g4+3], w4.w, a1);
      }
    }
    acc0[dd] = a0; acc1[dd] = a1;
  }

  // LN2 via quad-sum DPP, both sets
  unsigned zq20[16], zq21[16];
  {
    float s0s = 0.f, s1s = 0.f;
    #pragma unroll
    for (int dd = 0; dd < DH; ++dd) { s0s += acc0[dd]; s1s += acc1[dd]; }
    s0s += qdppf<0xB1>(s0s); s0s += qdppf<0x4E>(s0s);
    s1s += qdppf<0xB1>(s1s); s1s += qdppf<0x4E>(s1s);
    float m0 = s0s * (1.0f/DD), m1 = s1s * (1.0f/DD);
    float v0 = 0.f, v1 = 0.f;
    #pragma unroll
    for (int dd = 0; dd < DH; ++dd) {
      float d0 = acc0[dd]-m0; v0 += d0*d0;
      float d1 = acc1[dd]-m1; v1 += d1*d1;
    }
    v0 += qdppf<0xB1>(v0); v0 += qdppf<0x4E>(v0);
    v1 += qdppf<0xB1>(v1); v1 += qdppf<0x4E>(v1);
    float r0 = rsqrtf(v0*(1.0f/DD) + 1e-5f);
    float r1 = rsqrtf(v1*(1.0f/DD) + 1e-5f);
    unsigned za0[4], za1[4];
    #pragma unroll
    for (int j = 0; j < 4; ++j) {
      int d = hh*DH + 2*j;
      float x0 = (acc0[2*j]  -m0)*r0*g2[e0*DD+d]   + bb2[e0*DD+d];
      float y0 = (acc0[2*j+1]-m0)*r0*g2[e0*DD+d+1] + bb2[e0*DD+d+1];
      float x1 = (acc1[2*j]  -m1)*r1*g2[e1*DD+d]   + bb2[e1*DD+d];
      float y1 = (acc1[2*j+1]-m1)*r1*g2[e1*DD+d+1] + bb2[e1*DD+d+1];
      za0[j] = pkh2(x0, y0);
      za1[j] = pkh2(x1, y1);
    }
    #pragma unroll
    for (int j = 0; j < 4; ++j) {
      zq20[j]    = qdpp<0x00>(za0[j]);  zq21[j]    = qdpp<0x00>(za1[j]);
      zq20[4+j]  = qdpp<0x55>(za0[j]);  zq21[4+j]  = qdpp<0x55>(za1[j]);
      zq20[8+j]  = qdpp<0xAA>(za0[j]);  zq21[8+j]  = qdpp<0xAA>(za1[j]);
      zq20[12+j] = qdpp<0xFF>(za0[j]);  zq21[12+j] = qdpp<0xFF>(za1[j]);
    }
  }

  // FFN1: f[hh*16 .. +16) for both sets
  float f0[16], f1[16];
  #pragma unroll
  for (int jj = 0; jj < 16; ++jj) {
    const uint4* row0 = (const uint4*)&wl[2048 + (e0*64 + jj*4 + hh)*16];
    float a0 = b1[e0*DFFN + hh*16 + jj];
    float a1 = b1[e1*DFFN + hh*16 + jj];
    #pragma unroll
    for (int g4 = 0; g4 < 4; ++g4) {
      uint4 w4 = row0[g4];
      a0 = fd2(zq20[4*g4+0], w4.x, a0); a0 = fd2(zq20[4*g4+1], w4.y, a0);
      a0 = fd2(zq20[4*g4+2], w4.z, a0); a0 = fd2(zq20[4*g4+3], w4.w, a0);
      if (same_e) {
        a1 = fd2(zq21[4*g4+0], w4.x, a1); a1 = fd2(zq21[4*g4+1], w4.y, a1);
        a1 = fd2(zq21[4*g4+2], w4.z, a1); a1 = fd2(zq21[4*g4+3], w4.w, a1);
      }
    }
    if (!same_e) {
      const uint4* row1 = (const uint4*)&wl[2048 + (e1*64 + jj*4 + hh)*16];
      #pragma unroll
      for (int g4 = 0; g4 < 4; ++g4) {
        uint4 w4 = row1[g4];
        a1 = fd2(zq21[4*g4+0], w4.x, a1); a1 = fd2(zq21[4*g4+1], w4.y, a1);
        a1 = fd2(zq21[4*g4+2], w4.z, a1); a1 = fd2(zq21[4*g4+3], w4.w, a1);
      }
    }
    f0[jj] = fmaxf(a0, 0.0f);
    f1[jj] = fmaxf(a1, 0.0f);
  }
  // f gather via DPP
  unsigned fu0[32], fu1[32];
  {
    unsigned fq0[8], fq1[8];
    #pragma unroll
    for (int j = 0; j < 8; ++j) {
      fq0[j] = pkh2(f0[2*j], f0[2*j+1]);
      fq1[j] = pkh2(f1[2*j], f1[2*j+1]);
    }
    #pragma unroll
    for (int j = 0; j < 8; ++j) {
      fu0[j]    = qdpp<0x00>(fq0[j]);  fu1[j]    = qdpp<0x00>(fq1[j]);
      fu0[8+j]  = qdpp<0x55>(fq0[j]);  fu1[8+j]  = qdpp<0x55>(fq1[j]);
      fu0[16+j] = qdpp<0xAA>(fq0[j]);  fu1[16+j] = qdpp<0xAA>(fq1[j]);
      fu0[24+j] = qdpp<0xFF>(fq0[j]);  fu1[24+j] = qdpp<0xFF>(fq1[j]);
    }
  }

  // FFN2 + residual + b2, both sets
  float acc20[DH], acc21[DH];
  #pragma unroll
  for (int dd = 0; dd < DH; ++dd) {
    const int d = hh*DH + dd;
    const int r160 = (e0*32 + dd*4 + hh)*16;
    float a0 = acc0[dd] + b2[e0*DD + d];
    float a1 = acc1[dd] + b2[e1*DD + d];
    #pragma unroll
    for (int g4 = 0; g4 < 8; ++g4) {
      const int plane = (g4 >> 2);
      uint4 w4 = *(const uint4*)&wl[6144 + plane*2048 + r160 + 4*(g4 & 3)];
      a0 = fd2(fu0[4*g4+0], w4.x, a0); a0 = fd2(fu0[4*g4+1], w4.y, a0);
      a0 = fd2(fu0[4*g4+2], w4.z, a0); a0 = fd2(fu0[4*g4+3], w4.w, a0);
      if (same_e) {
        a1 = fd2(fu1[4*g4+0], w4.x, a1); a1 = fd2(fu1[4*g4+1], w4.y, a1);
        a1 = fd2(fu1[4*g4+2], w4.z, a1); a1 = fd2(fu1[4*g4+3], w4.w, a1);
      }
    }
    if (!same_e) {
      const int r161 = (e1*32 + dd*4 + hh)*16;
      #pragma unroll
      for (int g4 = 0; g4 < 8; ++g4) {
        const int plane = (g4 >> 2);
        uint4 w4 = *(const uint4*)&wl[6144 + plane*2048 + r161 + 4*(g4 & 3)];
        a1 = fd2(fu1[4*g4+0], w4.x, a1); a1 = fd2(fu1[4*g4+1], w4.y, a1);
        a1 = fd2(fu1[4*g4+2], w4.z, a1); a1 = fd2(fu1[4*g4+3], w4.w, a1);
      }
    }
    acc20[dd] = a0; acc21[dd] = a1;
  }
  float* op0 = out + ((size_t)((b*SS + sA)*NCH + n))*DD + hh*DH;
  *(float4*)(op0)     = make_float4(acc20[0], acc20[1], acc20[2], acc20[3]);
  *(float4*)(op0 + 4) = make_float4(acc20[4], acc20[5], acc20[6], acc20[7]);
  float* op1 = out + ((size_t)((b*SS + sB)*NCH + n))*DD + hh*DH;
  *(float4*)(op1)     = make_float4(acc21[0], acc21[1], acc21[2], acc21[3]);
  *(float4*)(op1 + 4) = make_float4(acc21[4], acc21[5], acc21[6], acc21[7]);
}

// ---------------------------------------------------------------------------
extern "C" void kernel_launch(void* const* d_in, const int* in_sizes, int n_in,
                              void* d_out, int out_size, void* d_ws, size_t ws_size,
                              hipStream_t stream) {
  (void)in_sizes; (void)n_in; (void)out_size; (void)ws_size;
  const float* x   = (const float*)d_in[0];
  const float* ox  = (const float*)d_in[1];
  const float* sW  = (const float*)d_in[2];
  const float* sb  = (const float*)d_in[3];
  const float* Wq  = (const float*)d_in[4];
  const float* Wk  = (const float*)d_in[5];
  const float* Wv  = (const float*)d_in[6];
  const float* Wo  = (const float*)d_in[7];
  const float* g1  = (const float*)d_in[8];
  const float* b1n = (const float*)d_in[9];
  const float* g2  = (const float*)d_in[10];
  const float* b2n = (const float*)d_in[11];
  const float* W1  = (const float*)d_in[12];
  const float* bf1 = (const float*)d_in[13];
  const float* W2  = (const float*)d_in[14];
  const float* bf2 = (const float*)d_in[15];
  float* out = (float*)d_out;
  float* ws  = (float*)d_ws;

  decomp_prep_kernel<<<276, 1024, 0, stream>>>(x, ox, sb, g1, b1n,
                                               Wq, Wk, Wv, Wo, W1, W2, ws);
  fused_kernel<<<BB*NCH, 512, 0, stream>>>(ws, g1, b1n, sW, sb, g2, b2n,
                                           bf1, bf2, out);
}

// Round 12
// 224.317 us; speedup vs baseline: 1.0614x; 1.0614x over previous
//
#include <hip/hip_runtime.h>
#include <hip/hip_fp16.h>
#include <math.h>

#define BB 16
#define SS 256
#define CC 17
#define NCH 16
#define DD 32
#define DFFN 64
#define HH 4
#define DH 8
#define EE 4

// ws layout (4-byte units):
//  [16 ..143]  K0[e][d]   [144..271] V0[e][d]
//  [512..66047]  XNS[b][s][n]
//  ints at WS_SPI: SP[b][p] (4096), OFF[b][e] (64)
//  WS_WT: weight images (16384 uints): WqT/WkT/WvT 6144 | WoT 2048 | W1T 4096 | W2T 2x2048
#define WS_K0 16
#define WS_V0 144
#define WS_XNS 512
#define WS_SPI (WS_XNS + BB*SS*NCH)          // 66048
#define WS_WT  (WS_SPI + BB*SS + 64)         // 70208
#define WS_WL  (WS_WT + 6144)

#define PRE 0.51006977f   // (1/sqrt(8)) * log2(e)

typedef __fp16 hv2 __attribute__((ext_vector_type(2)));

__device__ __forceinline__ unsigned pkh2(float a, float b) {
  hv2 r = __builtin_amdgcn_cvt_pkrtz(a, b);
  unsigned u; __builtin_memcpy(&u, &r, 4);
  return u;
}
__device__ __forceinline__ float fd2(unsigned a, unsigned b, float c) {
  hv2 av, bv;
  __builtin_memcpy(&av, &a, 4);
  __builtin_memcpy(&bv, &b, 4);
  return __builtin_amdgcn_fdot2(av, bv, c, false);
}
__device__ __forceinline__ __half2 u2h2(unsigned u) {
  __half2 h; __builtin_memcpy(&h, &u, 4); return h;
}
template<int PAT>
__device__ __forceinline__ unsigned qdpp(unsigned v) {
  return (unsigned)__builtin_amdgcn_mov_dpp((int)v, PAT, 0xF, 0xF, true);
}
template<int PAT>
__device__ __forceinline__ float qdppf(float v) {
  return __uint_as_float(qdpp<PAT>(__float_as_uint(v)));
}

// ---------------------------------------------------------------------------
// Kernel 1 (1024 thr): decomp (blocks 0..255), prep (256..271),
// weight-image convert (272..275). [unchanged]
// ---------------------------------------------------------------------------
__launch_bounds__(1024)
__global__ void decomp_prep_kernel(const float* __restrict__ x,
                                   const float* __restrict__ ox,
                                   const float* __restrict__ sb,
                                   const float* __restrict__ g1,
                                   const float* __restrict__ bb1,
                                   const float* __restrict__ Wq,
                                   const float* __restrict__ Wk,
                                   const float* __restrict__ Wv,
                                   const float* __restrict__ Wo,
                                   const float* __restrict__ W1,
                                   const float* __restrict__ W2,
                                   float* __restrict__ ws) {
  const int t = threadIdx.x;  // 1024
  if (blockIdx.x < 256) {
    const int b = blockIdx.x / NCH;
    const int c = blockIdx.x % NCH;
    __shared__ float xs[SS];
    __shared__ float prr[1024], pii[1024];
    __shared__ float amp[129];
    __shared__ float2 YY[129];
    __shared__ float sth;
    if (t < SS) xs[t] = x[(b*SS + t)*CC + c];
    __syncthreads();
    const float TH0 = 0.024543692606170259f;  // 2*pi/256
    {
      const int f = (t & 127) + 1;
      const int chunk = t >> 7;
      const int s0 = chunk * 32;
      const int ph0 = (f * s0) & 255;
      float si, cr; sincosf(TH0*(float)ph0, &si, &cr);
      float s1, c1; sincosf(TH0*(float)f, &s1, &c1);
      float xr = 0.f, xi = 0.f;
      #pragma unroll 4
      for (int k = 0; k < 32; ++k) {
        float xvv = xs[s0 + k];
        xr += xvv * cr;
        xi -= xvv * si;
        float nc = cr*c1 - si*s1;
        si = si*c1 + cr*s1;
        cr = nc;
      }
      prr[t] = xr; pii[t] = xi;
    }
    __syncthreads();
    if (t < 128) {
      float xr = 0.f, xi = 0.f;
      #pragma unroll
      for (int k2 = 0; k2 < 8; ++k2) { xr += prr[t + 128*k2]; xi += pii[t + 128*k2]; }
      prr[t] = xr; pii[t] = xi;
      amp[t+1] = sqrtf(xr*xr + xi*xi);
    }
    __syncthreads();
    if (t < 64) {
      float a0 = amp[t+1], a1 = amp[t+65];
      int i0 = t+1, i1 = t+65;
      float th = -1e30f;
      for (int r = 0; r < 4; ++r) {
        float mv = (a0 > a1) ? a0 : a1;
        int   mi = (a0 > a1) ? i0 : i1;
        for (int off = 32; off > 0; off >>= 1) {
          float ov = __shfl_xor(mv, off);
          int   oi = __shfl_xor(mi, off);
          if (ov > mv || (ov == mv && oi < mi)) { mv = ov; mi = oi; }
        }
        th = mv;
        if (mi == i0) a0 = -1e30f;
        if (mi == i1) a1 = -1e30f;
      }
      if (t == 0) sth = th;
    }
    __syncthreads();
    if (t < 128) {
      const int f = t + 1;
      float wgt = (amp[f] >= sth) ? ((f == 128) ? 1.0f : 2.0f) * (1.0f/256.0f) : 0.0f;
      YY[f] = make_float2(wgt * prr[t], wgt * pii[t]);
    }
    __syncthreads();
    {
      const int s = t & 255;
      const int fc = t >> 8;
      const int f0 = 1 + fc*32;
      const int ph0 = (s * f0) & 255;
      float si, cr; sincosf(TH0*(float)ph0, &si, &cr);
      float s1, c1; sincosf(TH0*(float)s, &s1, &c1);
      float acc = 0.f;
      #pragma unroll 4
      for (int k = 0; k < 32; ++k) {
        float2 y = YY[f0 + k];
        acc += y.x*cr - y.y*si;
        float nc = cr*c1 - si*s1;
        si = si*c1 + cr*s1;
        cr = nc;
      }
      prr[t] = acc;
    }
    __syncthreads();
    if (t < 256) {
      float season = prr[t] + prr[t+256] + prr[t+512] + prr[t+768];
      float s4 = 0.f, s8 = 0.f, s12 = 0.f;
      #pragma unroll
      for (int j = 0; j < 4; ++j)  { int p = t + j - 1; p = p < 0 ? 0 : (p > SS-1 ? SS-1 : p); s4  += xs[p]; }
      #pragma unroll
      for (int j = 0; j < 8; ++j)  { int p = t + j - 3; p = p < 0 ? 0 : (p > SS-1 ? SS-1 : p); s8  += xs[p]; }
      #pragma unroll
      for (int j = 0; j < 12; ++j) { int p = t + j - 5; p = p < 0 ? 0 : (p > SS-1 ? SS-1 : p); s12 += xs[p]; }
      float trend = (s4 * 0.25f + s8 * 0.125f + s12 * (1.0f/12.0f)) * (1.0f/3.0f);
      ws[WS_XNS + (b*SS + t)*NCH + c] = xs[t] + season + trend;
    }
  } else if (blockIdx.x < 272) {
    const int b = blockIdx.x - 256;
    __shared__ float red[32];
    __shared__ int asg[SS];
    __shared__ int cnt[EE];
    __shared__ float z0[EE*DD];
    float mn = 3e38f, mx = -3e38f;
    #pragma unroll
    for (int k = 0; k < 4; ++k) {
      float v = ox[(t + k*1024)*2 + 1];
      mn = fminf(mn, v); mx = fmaxf(mx, v);
    }
    for (int off = 32; off > 0; off >>= 1) {
      mn = fminf(mn, __shfl_xor(mn, off));
      mx = fmaxf(mx, __shfl_xor(mx, off));
    }
    if ((t & 63) == 0) { red[(t>>6)*2] = mn; red[(t>>6)*2+1] = mx; }
    __syncthreads();
    mn = red[0]; mx = red[1];
    #pragma unroll
    for (int w = 1; w < 16; ++w) { mn = fminf(mn, red[w*2]); mx = fmaxf(mx, red[w*2+1]); }
    const float step = (mx - mn) * 0.25f;
    const float e1 = mn + step, e2 = mn + 2.f*step, e3 = mn + 3.f*step;
    if (t < 256) {
      float sc = ox[(b*SS + t)*2 + 1];
      asg[t] = (sc >= e1) + (sc >= e2) + (sc >= e3);
    }
    __syncthreads();
    if (t < EE) {
      int c = 0;
      for (int s2 = 0; s2 < SS; ++s2) c += (asg[s2] == t);
      cnt[t] = c;
    }
    __syncthreads();
    int* SPw  = (int*)ws + WS_SPI;
    int* OFFw = SPw + BB*SS;
    if (t < EE) {
      int off = 0;
      for (int i = 0; i < t; ++i) off += cnt[i];
      OFFw[b*EE + t] = off;
      int kp = off;
      for (int s2 = 0; s2 < SS; ++s2) if (asg[s2] == t) SPw[b*SS + (kp++)] = s2;
    }
    if (t < 128) {
      int ee = t >> 5, d = t & 31;
      float m = 0.f;
      for (int i = 0; i < DD; ++i) m += sb[i];
      m *= (1.0f/DD);
      float var = 0.f;
      for (int i = 0; i < DD; ++i) { float df = sb[i]-m; var += df*df; }
      var *= (1.0f/DD);
      float rs = rsqrtf(var + 1e-5f);
      z0[ee*DD + d] = (sb[d]-m)*rs*g1[ee*DD+d] + bb1[ee*DD+d];
    }
    __syncthreads();
    if (b == 0 && t < 128) {
      int ee = t >> 5, d = t & 31;
      float k0 = 0.f, v0 = 0.f;
      for (int i = 0; i < DD; ++i) {
        float zz = z0[ee*DD + i];
        k0 += zz * Wk[ee*DD*DD + i*DD + d];
        v0 += zz * Wv[ee*DD*DD + i*DD + d];
      }
      ws[WS_K0 + ee*DD + d] = k0;
      ws[WS_V0 + ee*DD + d] = v0;
    }
  } else {
    unsigned* img = (unsigned*)ws + WS_WT;
    const int base_u = (blockIdx.x - 272)*4096;
    #pragma unroll
    for (int i = 0; i < 4; ++i) {
      int u = base_u + i*1024 + t;
      unsigned val;
      if (u < 6144) {                    // Wq/Wk/Wv T
        int mat = u >> 11, r = u & 2047;
        int row = r >> 4, ip = r & 15;
        int e = row >> 5, q = row & 31;
        int d = (q & 3)*8 + (q >> 2);
        const float* Wm = (mat == 0) ? Wq : (mat == 1) ? Wk : Wv;
        const float* src = Wm + e*1024 + d;
        val = pkh2(src[ip*64], src[ip*64 + 32]);
      } else {
        int v = u - 6144;
        if (v < 2048) {                  // WoT
          int row = v >> 4, ip = v & 15;
          int e = row >> 5, q = row & 31;
          int d = (q & 3)*8 + (q >> 2);
          const float* src = Wo + e*1024 + d;
          val = pkh2(src[ip*64], src[ip*64 + 32]);
        } else if (v < 6144) {           // W1T
          int r = v - 2048;
          int row = r >> 4, ip = r & 15;
          int e = row >> 6, q = row & 63;
          int j = (q & 3)*16 + (q >> 2);
          const float* src = W1 + e*2048 + j;
          val = pkh2(src[ip*128], src[ip*128 + 64]);
        } else {                         // W2T (two planes)
          int r = v - 6144;
          int a = r >> 11, rr = r & 2047;
          int row = rr >> 4, ip = rr & 15;
          int e = row >> 5, q = row & 31;
          int d = (q & 3)*8 + (q >> 2);
          int jp = a*16 + ip;
          const float* src = W2 + e*2048 + d;
          val = pkh2(src[2*jp*32], src[(2*jp+1)*32]);
        }
      }
      img[u] = val;
    }
  }
}

// ---------------------------------------------------------------------------
// Kernel 2: fused, 2 positions/thread, SERIALIZED epilogue (low VGPR).
// Grid (b,n)=256 x 512 thr. launch_bounds(512,1): 256-VGPR budget, no spill.
// Attention iterates union segment once (k/v reads serve both positions).
// ---------------------------------------------------------------------------
__launch_bounds__(512, 1)
__global__ void fused_kernel(const float* __restrict__ ws,
    const float* __restrict__ g1, const float* __restrict__ bb1,
    const float* __restrict__ sW, const float* __restrict__ sb,
    const float* __restrict__ g2, const float* __restrict__ bb2,
    const float* __restrict__ b1, const float* __restrict__ b2,
    float* __restrict__ out) {
  const int blk = blockIdx.x;
  const int n = blk & 15;
  const int b = blk >> 4;
  const int t = threadIdx.x;      // 0..511
  const int pp = t >> 2;          // 0..127
  const int hh = t & 3;
  const int p0 = pp*2, p1 = pp*2 + 1;
  __shared__ unsigned lds[24576];
  unsigned* wT = lds + 8192;
  unsigned* wl = lds + 14336;

  // async-stage weight images (16384 uints = 64 x 1KB chunks, 8/wave)
  {
    const unsigned* img = (const unsigned*)ws + WS_WT;
    const int wv = t >> 6;
    const int ln = t & 63;
    #pragma unroll
    for (int i = 0; i < 8; ++i) {
      const int ch = wv*8 + i;
      __builtin_amdgcn_global_load_lds(
          (const __attribute__((address_space(1))) unsigned*)(img + ch*256 + ln*4),
          (__attribute__((address_space(3))) unsigned*)(wT + ch*256 + ln*4),
          16, 0, 0);
    }
  }

  const int* SP  = (const int*)ws + WS_SPI;
  const int* OFF = SP + BB*SS;
  const int o1 = OFF[b*4+1], o2v = OFF[b*4+2], o3 = OFF[b*4+3];
  const int e0 = (p0 >= o1) + (p0 >= o2v) + (p0 >= o3);
  const int e1 = (p1 >= o1) + (p1 >= o2v) + (p1 >= o3);
  const bool same_e = (e0 == e1);
  const int beg0 = (e0==0) ? 0  : ((e0==1) ? o1 : ((e0==2) ? o2v : o3));
  const int end0 = (e0==0) ? o1 : ((e0==1) ? o2v : ((e0==2) ? o3 : SS));
  const int beg1 = (e1==0) ? 0  : ((e1==1) ? o1 : ((e1==2) ? o2v : o3));
  const int end1 = (e1==0) ? o1 : ((e1==1) ? o2v : ((e1==2) ? o3 : SS));
  const int sA = SP[b*SS + p0];
  const int sB = SP[b*SS + p1];
  const float xv0 = ws[WS_XNS + (b*SS + sA)*NCH + n];
  const float xv1 = ws[WS_XNS + (b*SS + sB)*NCH + n];

  // LN1 for both positions
  unsigned zp0[16], zp1[16];
  {
    float h[DD];
    #pragma unroll
    for (int d = 0; d < DD; ++d) h[d] = xv0 * sW[d] + sb[d];
    float m = 0.f;
    #pragma unroll
    for (int d = 0; d < DD; ++d) m += h[d];
    m *= (1.0f/DD);
    float var = 0.f;
    #pragma unroll
    for (int d = 0; d < DD; ++d) { float df = h[d]-m; var += df*df; }
    float rs = rsqrtf(var*(1.0f/DD) + 1e-5f);
    #pragma unroll
    for (int ip = 0; ip < 16; ++ip) {
      float za = (h[2*ip]  -m)*rs*g1[e0*DD+2*ip]   + bb1[e0*DD+2*ip];
      float zb = (h[2*ip+1]-m)*rs*g1[e0*DD+2*ip+1] + bb1[e0*DD+2*ip+1];
      zp0[ip] = pkh2(za, zb);
    }
  }
  {
    float h[DD];
    #pragma unroll
    for (int d = 0; d < DD; ++d) h[d] = xv1 * sW[d] + sb[d];
    float m = 0.f;
    #pragma unroll
    for (int d = 0; d < DD; ++d) m += h[d];
    m *= (1.0f/DD);
    float var = 0.f;
    #pragma unroll
    for (int d = 0; d < DD; ++d) { float df = h[d]-m; var += df*df; }
    float rs = rsqrtf(var*(1.0f/DD) + 1e-5f);
    #pragma unroll
    for (int ip = 0; ip < 16; ++ip) {
      float za = (h[2*ip]  -m)*rs*g1[e1*DD+2*ip]   + bb1[e1*DD+2*ip];
      float zb = (h[2*ip+1]-m)*rs*g1[e1*DD+2*ip+1] + bb1[e1*DD+2*ip+1];
      zp1[ip] = pkh2(za, zb);
    }
  }
  __syncthreads();   // barrier 1: weight images staged

  // qkv for both positions; weight rows shared when same_e
  float q0[DH], q1[DH];
  {
    float kk0[DH], kk1[DH], vv0[DH], vv1[DH];
    #pragma unroll
    for (int dd = 0; dd < DH; ++dd) {
      const int r0 = (e0*32 + dd*4 + hh)*16;
      const uint4* rq = (const uint4*)&wT[r0];
      const uint4* rk = (const uint4*)&wT[2048 + r0];
      const uint4* rv = (const uint4*)&wT[4096 + r0];
      float aq0=0.f, ak0=0.f, av0=0.f, aq1=0.f, ak1=0.f, av1=0.f;
      #pragma unroll
      for (int g4 = 0; g4 < 4; ++g4) {
        uint4 wq4 = rq[g4], wk4 = rk[g4], wv4 = rv[g4];
        aq0 = fd2(zp0[4*g4+0], wq4.x, aq0); aq0 = fd2(zp0[4*g4+1], wq4.y, aq0);
        aq0 = fd2(zp0[4*g4+2], wq4.z, aq0); aq0 = fd2(zp0[4*g4+3], wq4.w, aq0);
        ak0 = fd2(zp0[4*g4+0], wk4.x, ak0); ak0 = fd2(zp0[4*g4+1], wk4.y, ak0);
        ak0 = fd2(zp0[4*g4+2], wk4.z, ak0); ak0 = fd2(zp0[4*g4+3], wk4.w, ak0);
        av0 = fd2(zp0[4*g4+0], wv4.x, av0); av0 = fd2(zp0[4*g4+1], wv4.y, av0);
        av0 = fd2(zp0[4*g4+2], wv4.z, av0); av0 = fd2(zp0[4*g4+3], wv4.w, av0);
        if (same_e) {
          aq1 = fd2(zp1[4*g4+0], wq4.x, aq1); aq1 = fd2(zp1[4*g4+1], wq4.y, aq1);
          aq1 = fd2(zp1[4*g4+2], wq4.z, aq1); aq1 = fd2(zp1[4*g4+3], wq4.w, aq1);
          ak1 = fd2(zp1[4*g4+0], wk4.x, ak1); ak1 = fd2(zp1[4*g4+1], wk4.y, ak1);
          ak1 = fd2(zp1[4*g4+2], wk4.z, ak1); ak1 = fd2(zp1[4*g4+3], wk4.w, ak1);
          av1 = fd2(zp1[4*g4+0], wv4.x, av1); av1 = fd2(zp1[4*g4+1], wv4.y, av1);
          av1 = fd2(zp1[4*g4+2], wv4.z, av1); av1 = fd2(zp1[4*g4+3], wv4.w, av1);
        }
      }
      if (!same_e) {
        const int r1 = (e1*32 + dd*4 + hh)*16;
        const uint4* rq1p = (const uint4*)&wT[r1];
        const uint4* rk1p = (const uint4*)&wT[2048 + r1];
        const uint4* rv1p = (const uint4*)&wT[4096 + r1];
        #pragma unroll
        for (int g4 = 0; g4 < 4; ++g4) {
          uint4 wq4 = rq1p[g4], wk4 = rk1p[g4], wv4 = rv1p[g4];
          aq1 = fd2(zp1[4*g4+0], wq4.x, aq1); aq1 = fd2(zp1[4*g4+1], wq4.y, aq1);
          aq1 = fd2(zp1[4*g4+2], wq4.z, aq1); aq1 = fd2(zp1[4*g4+3], wq4.w, aq1);
          ak1 = fd2(zp1[4*g4+0], wk4.x, ak1); ak1 = fd2(zp1[4*g4+1], wk4.y, ak1);
          ak1 = fd2(zp1[4*g4+2], wk4.z, ak1); ak1 = fd2(zp1[4*g4+3], wk4.w, ak1);
          av1 = fd2(zp1[4*g4+0], wv4.x, av1); av1 = fd2(zp1[4*g4+1], wv4.y, av1);
          av1 = fd2(zp1[4*g4+2], wv4.z, av1); av1 = fd2(zp1[4*g4+3], wv4.w, av1);
        }
      }
      q0[dd] = aq0 * PRE; kk0[dd] = ak0; vv0[dd] = av0;
      q1[dd] = aq1 * PRE; kk1[dd] = ak1; vv1[dd] = av1;
    }
    // write k/v for both positions
    *(uint4*)&lds[p0*32 + hh*8]     = make_uint4(pkh2(kk0[0],kk0[1]), pkh2(kk0[2],kk0[3]),
                                                 pkh2(kk0[4],kk0[5]), pkh2(kk0[6],kk0[7]));
    *(uint4*)&lds[p0*32 + hh*8 + 4] = make_uint4(pkh2(vv0[0],vv0[1]), pkh2(vv0[2],vv0[3]),
                                                 pkh2(vv0[4],vv0[5]), pkh2(vv0[6],vv0[7]));
    *(uint4*)&lds[p1*32 + hh*8]     = make_uint4(pkh2(kk1[0],kk1[1]), pkh2(kk1[2],kk1[3]),
                                                 pkh2(kk1[4],kk1[5]), pkh2(kk1[6],kk1[7]));
    *(uint4*)&lds[p1*32 + hh*8 + 4] = make_uint4(pkh2(vv1[0],vv1[1]), pkh2(vv1[2],vv1[3]),
                                                 pkh2(vv1[4],vv1[5]), pkh2(vv1[6],vv1[7]));
  }
  unsigned qp20[4], qp21[4];
  #pragma unroll
  for (int i = 0; i < 4; ++i) {
    qp20[i] = pkh2(q0[2*i], q0[2*i+1]);
    qp21[i] = pkh2(q1[2*i], q1[2*i+1]);
  }
  float sc0 = 0.f, sc1 = 0.f;
  #pragma unroll
  for (int d = 0; d < DH; ++d) {
    sc0 += q0[d] * ws[WS_K0 + e0*DD + hh*DH + d];
    sc1 += q1[d] * ws[WS_K0 + e1*DD + hh*DH + d];
  }
  __syncthreads();   // barrier 2: kv staged — LAST barrier

  // attention over union [beg0, end1): k/v read once, used for both positions
  float wsum0 = 0.f, wsum1 = 0.f;
  __half2 oa[4], ob[4];
  #pragma unroll
  for (int i = 0; i < 4; ++i) { oa[i] = u2h2(0u); ob[i] = u2h2(0u); }
  for (int j = beg0; j < end1; ++j) {
    uint4 ku = *(const uint4*)&lds[j*32 + hh*8];
    uint4 vu = *(const uint4*)&lds[j*32 + hh*8 + 4];
    float a0 = 0.f, a1 = 0.f;
    a0 = fd2(qp20[0], ku.x, a0); a0 = fd2(qp20[1], ku.y, a0);
    a0 = fd2(qp20[2], ku.z, a0); a0 = fd2(qp20[3], ku.w, a0);
    a1 = fd2(qp21[0], ku.x, a1); a1 = fd2(qp21[1], ku.y, a1);
    a1 = fd2(qp21[2], ku.z, a1); a1 = fd2(qp21[3], ku.w, a1);
    float w0k = (j < end0)  ? __builtin_amdgcn_exp2f(a0) : 0.f;
    float w1k = (j >= beg1) ? __builtin_amdgcn_exp2f(a1) : 0.f;
    wsum0 += w0k; wsum1 += w1k;
    __half2 w20 = u2h2(pkh2(w0k, w0k));
    __half2 w21 = u2h2(pkh2(w1k, w1k));
    oa[0] = __hfma2(w20, u2h2(vu.x), oa[0]);
    oa[1] = __hfma2(w20, u2h2(vu.y), oa[1]);
    oa[2] = __hfma2(w20, u2h2(vu.z), oa[2]);
    oa[3] = __hfma2(w20, u2h2(vu.w), oa[3]);
    ob[0] = __hfma2(w21, u2h2(vu.x), ob[0]);
    ob[1] = __hfma2(w21, u2h2(vu.y), ob[1]);
    ob[2] = __hfma2(w21, u2h2(vu.z), ob[2]);
    ob[3] = __hfma2(w21, u2h2(vu.w), ob[3]);
  }
  // finalize o for both positions, pack to 4 uints each
  unsigned oqa[4], oqb[4];
  {
    float o0[DH], o1v[DH];
    #pragma unroll
    for (int i = 0; i < 4; ++i) {
      o0[2*i]   = __low2float(oa[i]);  o0[2*i+1]  = __high2float(oa[i]);
      o1v[2*i]  = __low2float(ob[i]);  o1v[2*i+1] = __high2float(ob[i]);
    }
    const int nm0 = SS - (end0 - beg0);
    const int nm1 = SS - (end1 - beg1);
    float w00 = (float)nm0 * __builtin_amdgcn_exp2f(sc0);
    float w01 = (float)nm1 * __builtin_amdgcn_exp2f(sc1);
    wsum0 += w00; wsum1 += w01;
    #pragma unroll
    for (int d = 0; d < DH; ++d) {
      o0[d]  += w00 * ws[WS_V0 + e0*DD + hh*DH + d];
      o1v[d] += w01 * ws[WS_V0 + e1*DD + hh*DH + d];
    }
    float i0 = 1.0f / wsum0, i1 = 1.0f / wsum1;
    #pragma unroll
    for (int j = 0; j < 4; ++j) {
      oqa[j] = pkh2(o0[2*j]*i0, o0[2*j+1]*i0);
      oqb[j] = pkh2(o1v[2*j]*i1, o1v[2*j+1]*i1);
    }
  }

  // ---- SERIALIZED epilogue: one position at a time (bounded VGPR live set)
  #pragma unroll 2
  for (int sel = 0; sel < 2; ++sel) {
    const int   ee  = sel ? e1  : e0;
    const float xvv = sel ? xv1 : xv0;
    const int   ssx = sel ? sB  : sA;
    unsigned ovp[16];
    #pragma unroll
    for (int j = 0; j < 4; ++j) {
      unsigned src = sel ? oqb[j] : oqa[j];
      ovp[j]    = qdpp<0x00>(src);
      ovp[4+j]  = qdpp<0x55>(src);
      ovp[8+j]  = qdpp<0xAA>(src);
      ovp[12+j] = qdpp<0xFF>(src);
    }
    // Wo + residual
    float acc[DH];
    #pragma unroll
    for (int dd = 0; dd < DH; ++dd) {
      const int d = hh*DH + dd;
      const uint4* row = (const uint4*)&wl[(ee*32 + dd*4 + hh)*16];
      float a = xvv * sW[d] + sb[d];
      #pragma unroll
      for (int g4 = 0; g4 < 4; ++g4) {
        uint4 w4 = row[g4];
        a = fd2(ovp[4*g4+0], w4.x, a); a = fd2(ovp[4*g4+1], w4.y, a);
        a = fd2(ovp[4*g4+2], w4.z, a); a = fd2(ovp[4*g4+3], w4.w, a);
      }
      acc[dd] = a;
    }
    // LN2 via quad-sum DPP
    float ssum = 0.f;
    #pragma unroll
    for (int dd = 0; dd < DH; ++dd) ssum += acc[dd];
    ssum += qdppf<0xB1>(ssum);
    ssum += qdppf<0x4E>(ssum);
    float m2 = ssum * (1.0f/DD);
    float vs = 0.f;
    #pragma unroll
    for (int dd = 0; dd < DH; ++dd) { float df = acc[dd]-m2; vs += df*df; }
    vs += qdppf<0xB1>(vs);
    vs += qdppf<0x4E>(vs);
    float rs2 = rsqrtf(vs * (1.0f/DD) + 1e-5f);
    unsigned zp2[16];
    {
      unsigned zq[4];
      #pragma unroll
      for (int j = 0; j < 4; ++j) {
        int d = hh*DH + 2*j;
        float za = (acc[2*j]  -m2)*rs2*g2[ee*DD+d]   + bb2[ee*DD+d];
        float zb = (acc[2*j+1]-m2)*rs2*g2[ee*DD+d+1] + bb2[ee*DD+d+1];
        zq[j] = pkh2(za, zb);
      }
      #pragma unroll
      for (int j = 0; j < 4; ++j) {
        zp2[j]    = qdpp<0x00>(zq[j]);
        zp2[4+j]  = qdpp<0x55>(zq[j]);
        zp2[8+j]  = qdpp<0xAA>(zq[j]);
        zp2[12+j] = qdpp<0xFF>(zq[j]);
      }
    }
    // FFN1: f[hh*16 .. +16)
    unsigned fq[8];
    {
      float f[16];
      #pragma unroll
      for (int jj = 0; jj < 16; ++jj) {
        const uint4* row = (const uint4*)&wl[2048 + (ee*64 + jj*4 + hh)*16];
        float a = b1[ee*DFFN + hh*16 + jj];
        #pragma unroll
        for (int g4 = 0; g4 < 4; ++g4) {
          uint4 w4 = row[g4];
          a = fd2(zp2[4*g4+0], w4.x, a); a = fd2(zp2[4*g4+1], w4.y, a);
          a = fd2(zp2[4*g4+2], w4.z, a); a = fd2(zp2[4*g4+3], w4.w, a);
        }
        f[jj] = fmaxf(a, 0.0f);
      }
      #pragma unroll
      for (int j = 0; j < 8; ++j) fq[j] = pkh2(f[2*j], f[2*j+1]);
    }
    unsigned fu[32];
    #pragma unroll
    for (int j = 0; j < 8; ++j) {
      fu[j]    = qdpp<0x00>(fq[j]);
      fu[8+j]  = qdpp<0x55>(fq[j]);
      fu[16+j] = qdpp<0xAA>(fq[j]);
      fu[24+j] = qdpp<0xFF>(fq[j]);
    }
    // FFN2 + residual + b2
    float acc2[DH];
    #pragma unroll
    for (int dd = 0; dd < DH; ++dd) {
      const int d = hh*DH + dd;
      const int r16 = (ee*32 + dd*4 + hh)*16;
      float a = acc[dd] + b2[ee*DD + d];
      #pragma unroll
      for (int g4 = 0; g4 < 8; ++g4) {
        const int plane = (g4 >> 2);
        uint4 w4 = *(const uint4*)&wl[6144 + plane*2048 + r16 + 4*(g4 & 3)];
        a = fd2(fu[4*g4+0], w4.x, a); a = fd2(fu[4*g4+1], w4.y, a);
        a = fd2(fu[4*g4+2], w4.z, a); a = fd2(fu[4*g4+3], w4.w, a);
      }
      acc2[dd] = a;
    }
    float* op = out + ((size_t)((b*SS + ssx)*NCH + n))*DD + hh*DH;
    *(float4*)(op)     = make_float4(acc2[0], acc2[1], acc2[2], acc2[3]);
    *(float4*)(op + 4) = make_float4(acc2[4], acc2[5], acc2[6], acc2[7]);
  }
}

// ---------------------------------------------------------------------------
extern "C" void kernel_launch(void* const* d_in, const int* in_sizes, int n_in,
                              void* d_out, int out_size, void* d_ws, size_t ws_size,
                              hipStream_t stream) {
  (void)in_sizes; (void)n_in; (void)out_size; (void)ws_size;
  const float* x   = (const float*)d_in[0];
  const float* ox  = (const float*)d_in[1];
  const float* sW  = (const float*)d_in[2];
  const float* sb  = (const float*)d_in[3];
  const float* Wq  = (const float*)d_in[4];
  const float* Wk  = (const float*)d_in[5];
  const float* Wv  = (const float*)d_in[6];
  const float* Wo  = (const float*)d_in[7];
  const float* g1  = (const float*)d_in[8];
  const float* b1n = (const float*)d_in[9];
  const float* g2  = (const float*)d_in[10];
  const float* b2n = (const float*)d_in[11];
  const float* W1  = (const float*)d_in[12];
  const float* bf1 = (const float*)d_in[13];
  const float* W2  = (const float*)d_in[14];
  const float* bf2 = (const float*)d_in[15];
  float* out = (float*)d_out;
  float* ws  = (float*)d_ws;

  decomp_prep_kernel<<<276, 1024, 0, stream>>>(x, ox, sb, g1, b1n,
                                               Wq, Wk, Wv, Wo, W1, W2, ws);
  fused_kernel<<<BB*NCH, 512, 0, stream>>>(ws, g1, b1n, sW, sb, g2, b2n,
                                           bf1, bf2, out);
}

// Round 13
// 133.169 us; speedup vs baseline: 1.7879x; 1.6844x over previous
//
#include <hip/hip_runtime.h>
#include <hip/hip_fp16.h>
#include <math.h>

#define BB 16
#define SS 256
#define CC 17
#define NCH 16
#define DD 32
#define DFFN 64
#define HH 4
#define DH 8
#define EE 4

// ws layout (4-byte units):
//  [16 ..143]  K0[e][d]   [144..271] V0[e][d]
//  [512..66047]  XNS[b][s][n]
//  ints at WS_SPI: SP[b][p] (4096), OFF[b][e] (64)
//  WS_WT: weight images (16384 uints): WqT/WkT/WvT 6144 | WoT 2048 | W1T 4096 | W2T 2x2048
#define WS_K0 16
#define WS_V0 144
#define WS_XNS 512
#define WS_SPI (WS_XNS + BB*SS*NCH)          // 66048
#define WS_WT  (WS_SPI + BB*SS + 64)         // 70208
#define WS_WL  (WS_WT + 6144)

#define PRE 0.51006977f   // (1/sqrt(8)) * log2(e)

typedef __fp16 hv2 __attribute__((ext_vector_type(2)));

__device__ __forceinline__ unsigned pkh2(float a, float b) {
  hv2 r = __builtin_amdgcn_cvt_pkrtz(a, b);
  unsigned u; __builtin_memcpy(&u, &r, 4);
  return u;
}
__device__ __forceinline__ float fd2(unsigned a, unsigned b, float c) {
  hv2 av, bv;
  __builtin_memcpy(&av, &a, 4);
  __builtin_memcpy(&bv, &b, 4);
  return __builtin_amdgcn_fdot2(av, bv, c, false);
}
__device__ __forceinline__ __half2 u2h2(unsigned u) {
  __half2 h; __builtin_memcpy(&h, &u, 4); return h;
}
template<int PAT>
__device__ __forceinline__ unsigned qdpp(unsigned v) {
  return (unsigned)__builtin_amdgcn_mov_dpp((int)v, PAT, 0xF, 0xF, true);
}
template<int PAT>
__device__ __forceinline__ float qdppf(float v) {
  return __uint_as_float(qdpp<PAT>(__float_as_uint(v)));
}

// ---------------------------------------------------------------------------
// Kernel 1 (1024 thr): decomp (blocks 0..255), prep (256..271),
// weight-image convert (272..275).
// ---------------------------------------------------------------------------
__launch_bounds__(1024)
__global__ void decomp_prep_kernel(const float* __restrict__ x,
                                   const float* __restrict__ ox,
                                   const float* __restrict__ sb,
                                   const float* __restrict__ g1,
                                   const float* __restrict__ bb1,
                                   const float* __restrict__ Wq,
                                   const float* __restrict__ Wk,
                                   const float* __restrict__ Wv,
                                   const float* __restrict__ Wo,
                                   const float* __restrict__ W1,
                                   const float* __restrict__ W2,
                                   float* __restrict__ ws) {
  const int t = threadIdx.x;  // 1024
  if (blockIdx.x < 256) {
    const int b = blockIdx.x / NCH;
    const int c = blockIdx.x % NCH;
    __shared__ float xs[SS];
    __shared__ float prr[1024], pii[1024];
    __shared__ float amp[129];
    __shared__ float2 YY[129];
    __shared__ float sth;
    if (t < SS) xs[t] = x[(b*SS + t)*CC + c];
    __syncthreads();
    const float TH0 = 0.024543692606170259f;  // 2*pi/256
    {
      const int f = (t & 127) + 1;
      const int chunk = t >> 7;
      const int s0 = chunk * 32;
      const int ph0 = (f * s0) & 255;
      float si, cr; sincosf(TH0*(float)ph0, &si, &cr);
      float s1, c1; sincosf(TH0*(float)f, &s1, &c1);
      float xr = 0.f, xi = 0.f;
      #pragma unroll 4
      for (int k = 0; k < 32; ++k) {
        float xvv = xs[s0 + k];
        xr += xvv * cr;
        xi -= xvv * si;
        float nc = cr*c1 - si*s1;
        si = si*c1 + cr*s1;
        cr = nc;
      }
      prr[t] = xr; pii[t] = xi;
    }
    __syncthreads();
    if (t < 128) {
      float xr = 0.f, xi = 0.f;
      #pragma unroll
      for (int k2 = 0; k2 < 8; ++k2) { xr += prr[t + 128*k2]; xi += pii[t + 128*k2]; }
      prr[t] = xr; pii[t] = xi;
      amp[t+1] = sqrtf(xr*xr + xi*xi);
    }
    __syncthreads();
    if (t < 64) {   // wave 0: top-4 knockout
      float a0 = amp[t+1], a1 = amp[t+65];
      int i0 = t+1, i1 = t+65;
      float th = -1e30f;
      for (int r = 0; r < 4; ++r) {
        float mv = (a0 > a1) ? a0 : a1;
        int   mi = (a0 > a1) ? i0 : i1;
        for (int off = 32; off > 0; off >>= 1) {
          float ov = __shfl_xor(mv, off);
          int   oi = __shfl_xor(mi, off);
          if (ov > mv || (ov == mv && oi < mi)) { mv = ov; mi = oi; }
        }
        th = mv;
        if (mi == i0) a0 = -1e30f;
        if (mi == i1) a1 = -1e30f;
      }
      if (t == 0) sth = th;
    }
    __syncthreads();
    if (t < 128) {
      const int f = t + 1;
      float wgt = (amp[f] >= sth) ? ((f == 128) ? 1.0f : 2.0f) * (1.0f/256.0f) : 0.0f;
      YY[f] = make_float2(wgt * prr[t], wgt * pii[t]);
    }
    __syncthreads();
    {
      const int s = t & 255;
      const int fc = t >> 8;
      const int f0 = 1 + fc*32;
      const int ph0 = (s * f0) & 255;
      float si, cr; sincosf(TH0*(float)ph0, &si, &cr);
      float s1, c1; sincosf(TH0*(float)s, &s1, &c1);
      float acc = 0.f;
      #pragma unroll 4
      for (int k = 0; k < 32; ++k) {
        float2 y = YY[f0 + k];
        acc += y.x*cr - y.y*si;
        float nc = cr*c1 - si*s1;
        si = si*c1 + cr*s1;
        cr = nc;
      }
      prr[t] = acc;
    }
    __syncthreads();
    if (t < 256) {
      float season = prr[t] + prr[t+256] + prr[t+512] + prr[t+768];
      float s4 = 0.f, s8 = 0.f, s12 = 0.f;
      #pragma unroll
      for (int j = 0; j < 4; ++j)  { int p = t + j - 1; p = p < 0 ? 0 : (p > SS-1 ? SS-1 : p); s4  += xs[p]; }
      #pragma unroll
      for (int j = 0; j < 8; ++j)  { int p = t + j - 3; p = p < 0 ? 0 : (p > SS-1 ? SS-1 : p); s8  += xs[p]; }
      #pragma unroll
      for (int j = 0; j < 12; ++j) { int p = t + j - 5; p = p < 0 ? 0 : (p > SS-1 ? SS-1 : p); s12 += xs[p]; }
      float trend = (s4 * 0.25f + s8 * 0.125f + s12 * (1.0f/12.0f)) * (1.0f/3.0f);
      ws[WS_XNS + (b*SS + t)*NCH + c] = xs[t] + season + trend;
    }
  } else if (blockIdx.x < 272) {
    const int b = blockIdx.x - 256;
    __shared__ float red[32];
    __shared__ int asg[SS];
    __shared__ int cnt[EE];
    __shared__ float z0[EE*DD];
    float mn = 3e38f, mx = -3e38f;
    #pragma unroll
    for (int k = 0; k < 4; ++k) {
      float v = ox[(t + k*1024)*2 + 1];
      mn = fminf(mn, v); mx = fmaxf(mx, v);
    }
    for (int off = 32; off > 0; off >>= 1) {
      mn = fminf(mn, __shfl_xor(mn, off));
      mx = fmaxf(mx, __shfl_xor(mx, off));
    }
    if ((t & 63) == 0) { red[(t>>6)*2] = mn; red[(t>>6)*2+1] = mx; }
    __syncthreads();
    mn = red[0]; mx = red[1];
    #pragma unroll
    for (int w = 1; w < 16; ++w) { mn = fminf(mn, red[w*2]); mx = fmaxf(mx, red[w*2+1]); }
    const float step = (mx - mn) * 0.25f;
    const float e1 = mn + step, e2 = mn + 2.f*step, e3 = mn + 3.f*step;
    if (t < 256) {
      float sc = ox[(b*SS + t)*2 + 1];
      asg[t] = (sc >= e1) + (sc >= e2) + (sc >= e3);
    }
    __syncthreads();
    if (t < EE) {
      int c = 0;
      for (int s2 = 0; s2 < SS; ++s2) c += (asg[s2] == t);
      cnt[t] = c;
    }
    __syncthreads();
    int* SPw  = (int*)ws + WS_SPI;
    int* OFFw = SPw + BB*SS;
    if (t < EE) {
      int off = 0;
      for (int i = 0; i < t; ++i) off += cnt[i];
      OFFw[b*EE + t] = off;
      int kp = off;
      for (int s2 = 0; s2 < SS; ++s2) if (asg[s2] == t) SPw[b*SS + (kp++)] = s2;
    }
    if (t < 128) {
      int ee = t >> 5, d = t & 31;
      float m = 0.f;
      for (int i = 0; i < DD; ++i) m += sb[i];
      m *= (1.0f/DD);
      float var = 0.f;
      for (int i = 0; i < DD; ++i) { float df = sb[i]-m; var += df*df; }
      var *= (1.0f/DD);
      float rs = rsqrtf(var + 1e-5f);
      z0[ee*DD + d] = (sb[d]-m)*rs*g1[ee*DD+d] + bb1[ee*DD+d];
    }
    __syncthreads();
    if (b == 0 && t < 128) {
      int ee = t >> 5, d = t & 31;
      float k0 = 0.f, v0 = 0.f;
      for (int i = 0; i < DD; ++i) {
        float zz = z0[ee*DD + i];
        k0 += zz * Wk[ee*DD*DD + i*DD + d];
        v0 += zz * Wv[ee*DD*DD + i*DD + d];
      }
      ws[WS_K0 + ee*DD + d] = k0;
      ws[WS_V0 + ee*DD + d] = v0;
    }
  } else {
    unsigned* img = (unsigned*)ws + WS_WT;
    const int base_u = (blockIdx.x - 272)*4096;
    #pragma unroll
    for (int i = 0; i < 4; ++i) {
      int u = base_u + i*1024 + t;
      unsigned val;
      if (u < 6144) {                    // Wq/Wk/Wv T
        int mat = u >> 11, r = u & 2047;
        int row = r >> 4, ip = r & 15;
        int e = row >> 5, q = row & 31;
        int d = (q & 3)*8 + (q >> 2);
        const float* Wm = (mat == 0) ? Wq : (mat == 1) ? Wk : Wv;
        const float* src = Wm + e*1024 + d;
        val = pkh2(src[ip*64], src[ip*64 + 32]);
      } else {
        int v = u - 6144;
        if (v < 2048) {                  // WoT
          int row = v >> 4, ip = v & 15;
          int e = row >> 5, q = row & 31;
          int d = (q & 3)*8 + (q >> 2);
          const float* src = Wo + e*1024 + d;
          val = pkh2(src[ip*64], src[ip*64 + 32]);
        } else if (v < 6144) {           // W1T
          int r = v - 2048;
          int row = r >> 4, ip = r & 15;
          int e = row >> 6, q = row & 63;
          int j = (q & 3)*16 + (q >> 2);
          const float* src = W1 + e*2048 + j;
          val = pkh2(src[ip*128], src[ip*128 + 64]);
        } else {                         // W2T (two planes)
          int r = v - 6144;
          int a = r >> 11, rr = r & 2047;
          int row = rr >> 4, ip = rr & 15;
          int e = row >> 5, q = row & 31;
          int d = (q & 3)*8 + (q >> 2);
          int jp = a*16 + ip;
          const float* src = W2 + e*2048 + d;
          val = pkh2(src[2*jp*32], src[(2*jp+1)*32]);
        }
      }
      img[u] = val;
    }
  }
}

// ---------------------------------------------------------------------------
// Kernel 2: fused LN1+qkv+attn+Wo+LN2+FFN. Grid (b,n)=256 x 1024 thr.
// Two barriers; post-attention exchange via quad-lane DPP (lane quad = the 4
// head-threads of one position). LDS 96 KB: kv | wT | wl. VGPR 64, no spill.
// [R10 kernel — verified best: fused ~28 us, total 135.6 us]
// ---------------------------------------------------------------------------
__launch_bounds__(1024, 4)
__global__ void fused_kernel(const float* __restrict__ ws,
    const float* __restrict__ g1, const float* __restrict__ bb1,
    const float* __restrict__ sW, const float* __restrict__ sb,
    const float* __restrict__ g2, const float* __restrict__ bb2,
    const float* __restrict__ b1, const float* __restrict__ b2,
    float* __restrict__ out) {
  const int blk = blockIdx.x;
  const int n = blk & 15;
  const int b = blk >> 4;
  const int t = threadIdx.x;
  const int p = t >> 2;         // sorted position 0..255
  const int hh = t & 3;
  __shared__ unsigned lds[24576];
  unsigned* wT = lds + 8192;
  unsigned* wl = lds + 14336;

  // async-stage both weight images (16384 uints = 64 x 1KB chunks, 4/wave)
  {
    const unsigned* img = (const unsigned*)ws + WS_WT;
    const int wv = t >> 6;
    const int ln = t & 63;
    #pragma unroll
    for (int i = 0; i < 4; ++i) {
      const int ch = wv*4 + i;
      __builtin_amdgcn_global_load_lds(
          (const __attribute__((address_space(1))) unsigned*)(img + ch*256 + ln*4),
          (__attribute__((address_space(3))) unsigned*)(wT + ch*256 + ln*4),
          16, 0, 0);
    }
  }

  const int* SP  = (const int*)ws + WS_SPI;
  const int* OFF = SP + BB*SS;
  const int o1 = OFF[b*4+1], o2v = OFF[b*4+2], o3 = OFF[b*4+3];
  const int e = (p >= o1) + (p >= o2v) + (p >= o3);
  const int beg = (e==0) ? 0  : ((e==1) ? o1 : ((e==2) ? o2v : o3));
  const int end = (e==0) ? o1 : ((e==1) ? o2v : ((e==2) ? o3 : SS));
  const int s = SP[b*SS + p];
  const float xv = ws[WS_XNS + (b*SS + s)*NCH + n];

  // LN1 (replicated x4 per position; cheap)
  float h[DD];
  #pragma unroll
  for (int d = 0; d < DD; ++d) h[d] = xv * sW[d] + sb[d];
  float m = 0.f;
  #pragma unroll
  for (int d = 0; d < DD; ++d) m += h[d];
  m *= (1.0f/DD);
  float var = 0.f;
  #pragma unroll
  for (int d = 0; d < DD; ++d) { float df = h[d]-m; var += df*df; }
  var *= (1.0f/DD);
  float rs = rsqrtf(var + 1e-5f);
  unsigned zp[16];
  #pragma unroll
  for (int ip = 0; ip < 16; ++ip) {
    float za = (h[2*ip]  -m)*rs*g1[e*DD+2*ip]   + bb1[e*DD+2*ip];
    float zb = (h[2*ip+1]-m)*rs*g1[e*DD+2*ip+1] + bb1[e*DD+2*ip+1];
    zp[ip] = pkh2(za, zb);
  }
  __syncthreads();   // barrier 1: weight images staged (vmcnt drained)

  // qkv for this (p, hh) slice via fdot2
  float q[DH], kk[DH], vv[DH];
  #pragma unroll
  for (int dd = 0; dd < DH; ++dd) {
    const int row16 = (e*32 + dd*4 + hh)*16;    // permuted rows: hh low bits
    const uint4* rq = (const uint4*)&wT[row16];
    const uint4* rk = (const uint4*)&wT[2048 + row16];
    const uint4* rv = (const uint4*)&wT[4096 + row16];
    float aq = 0.f, ak = 0.f, av = 0.f;
    #pragma unroll
    for (int g4 = 0; g4 < 4; ++g4) {
      uint4 wq4 = rq[g4], wk4 = rk[g4], wv4 = rv[g4];
      aq = fd2(zp[4*g4+0], wq4.x, aq); aq = fd2(zp[4*g4+1], wq4.y, aq);
      aq = fd2(zp[4*g4+2], wq4.z, aq); aq = fd2(zp[4*g4+3], wq4.w, aq);
      ak = fd2(zp[4*g4+0], wk4.x, ak); ak = fd2(zp[4*g4+1], wk4.y, ak);
      ak = fd2(zp[4*g4+2], wk4.z, ak); ak = fd2(zp[4*g4+3], wk4.w, ak);
      av = fd2(zp[4*g4+0], wv4.x, av); av = fd2(zp[4*g4+1], wv4.y, av);
      av = fd2(zp[4*g4+2], wv4.z, av); av = fd2(zp[4*g4+3], wv4.w, av);
    }
    q[dd] = aq * PRE; kk[dd] = ak; vv[dd] = av;
  }
  // write k/v to LDS (f16 packed)
  *(uint4*)&lds[p*32 + hh*8]     = make_uint4(pkh2(kk[0],kk[1]), pkh2(kk[2],kk[3]),
                                              pkh2(kk[4],kk[5]), pkh2(kk[6],kk[7]));
  *(uint4*)&lds[p*32 + hh*8 + 4] = make_uint4(pkh2(vv[0],vv[1]), pkh2(vv[2],vv[3]),
                                              pkh2(vv[4],vv[5]), pkh2(vv[6],vv[7]));
  unsigned qp2[4];
  #pragma unroll
  for (int i = 0; i < 4; ++i) qp2[i] = pkh2(q[2*i], q[2*i+1]);
  float s0 = 0.f;
  #pragma unroll
  for (int d = 0; d < DH; ++d) s0 += q[d] * ws[WS_K0 + e*DD + hh*DH + d];
  __syncthreads();   // barrier 2: kv staged — LAST barrier

  // attention: o accumulated as packed f16 pairs (v_pk_fma_f16)
  float wsum = 0.f;
  __half2 o2[4];
  #pragma unroll
  for (int i = 0; i < 4; ++i) o2[i] = u2h2(0u);
  int jk = beg;
  for (; jk + 1 < end; jk += 2) {
    uint4 ku0 = *(const uint4*)&lds[jk*32 + hh*8];
    uint4 vu0 = *(const uint4*)&lds[jk*32 + hh*8 + 4];
    uint4 ku1 = *(const uint4*)&lds[(jk+1)*32 + hh*8];
    uint4 vu1 = *(const uint4*)&lds[(jk+1)*32 + hh*8 + 4];
    float a0 = 0.f, a1 = 0.f;
    a0 = fd2(qp2[0], ku0.x, a0); a0 = fd2(qp2[1], ku0.y, a0);
    a0 = fd2(qp2[2], ku0.z, a0); a0 = fd2(qp2[3], ku0.w, a0);
    a1 = fd2(qp2[0], ku1.x, a1); a1 = fd2(qp2[1], ku1.y, a1);
    a1 = fd2(qp2[2], ku1.z, a1); a1 = fd2(qp2[3], ku1.w, a1);
    float w0f = __builtin_amdgcn_exp2f(a0);
    float w1f = __builtin_amdgcn_exp2f(a1);
    wsum += w0f + w1f;
    __half2 w20 = u2h2(pkh2(w0f, w0f));
    __half2 w21 = u2h2(pkh2(w1f, w1f));
    o2[0] = __hfma2(w20, u2h2(vu0.x), o2[0]);
    o2[1] = __hfma2(w20, u2h2(vu0.y), o2[1]);
    o2[2] = __hfma2(w20, u2h2(vu0.z), o2[2]);
    o2[3] = __hfma2(w20, u2h2(vu0.w), o2[3]);
    o2[0] = __hfma2(w21, u2h2(vu1.x), o2[0]);
    o2[1] = __hfma2(w21, u2h2(vu1.y), o2[1]);
    o2[2] = __hfma2(w21, u2h2(vu1.z), o2[2]);
    o2[3] = __hfma2(w21, u2h2(vu1.w), o2[3]);
  }
  if (jk < end) {
    uint4 ku = *(const uint4*)&lds[jk*32 + hh*8];
    uint4 vu = *(const uint4*)&lds[jk*32 + hh*8 + 4];
    float a = 0.f;
    a = fd2(qp2[0], ku.x, a); a = fd2(qp2[1], ku.y, a);
    a = fd2(qp2[2], ku.z, a); a = fd2(qp2[3], ku.w, a);
    float wf = __builtin_amdgcn_exp2f(a);
    wsum += wf;
    __half2 w2 = u2h2(pkh2(wf, wf));
    o2[0] = __hfma2(w2, u2h2(vu.x), o2[0]);
    o2[1] = __hfma2(w2, u2h2(vu.y), o2[1]);
    o2[2] = __hfma2(w2, u2h2(vu.z), o2[2]);
    o2[3] = __hfma2(w2, u2h2(vu.w), o2[3]);
  }
  // off-expert keys: constant score s0, constant value v0
  float o[DH];
  #pragma unroll
  for (int i = 0; i < 4; ++i) {
    o[2*i]   = __low2float(o2[i]);
    o[2*i+1] = __high2float(o2[i]);
  }
  const int nmis = SS - (end - beg);
  float w0 = (float)nmis * __builtin_amdgcn_exp2f(s0);
  wsum += w0;
  #pragma unroll
  for (int d = 0; d < DH; ++d) o[d] += w0 * ws[WS_V0 + e*DD + hh*DH + d];
  float inv = 1.0f / wsum;
  #pragma unroll
  for (int d = 0; d < DH; ++d) o[d] *= inv;

  // ---- o gather via DPP quad broadcast (no barrier, no LDS) ----
  unsigned oq[4];
  #pragma unroll
  for (int j = 0; j < 4; ++j) oq[j] = pkh2(o[2*j], o[2*j+1]);
  unsigned ovp[16];
  #pragma unroll
  for (int j = 0; j < 4; ++j) {
    ovp[j]    = qdpp<0x00>(oq[j]);
    ovp[4+j]  = qdpp<0x55>(oq[j]);
    ovp[8+j]  = qdpp<0xAA>(oq[j]);
    ovp[12+j] = qdpp<0xFF>(oq[j]);
  }

  // Wo + residual: acc[dd] = h2 at dim hh*8+dd
  float acc[DH];
  #pragma unroll
  for (int dd = 0; dd < DH; ++dd) {
    int d = hh*DH + dd;
    const uint4* row = (const uint4*)&wl[(e*32 + dd*4 + hh)*16];
    float a = xv * sW[d] + sb[d];
    #pragma unroll
    for (int g4 = 0; g4 < 4; ++g4) {
      uint4 w4 = row[g4];
      a = fd2(ovp[4*g4+0], w4.x, a); a = fd2(ovp[4*g4+1], w4.y, a);
      a = fd2(ovp[4*g4+2], w4.z, a); a = fd2(ovp[4*g4+3], w4.w, a);
    }
    acc[dd] = a;
  }

  // ---- LN2 via quad-sum DPP reductions ----
  float ssum = 0.f;
  #pragma unroll
  for (int dd = 0; dd < DH; ++dd) ssum += acc[dd];
  ssum += qdppf<0xB1>(ssum);
  ssum += qdppf<0x4E>(ssum);
  float m2 = ssum * (1.0f/DD);
  float vs = 0.f;
  #pragma unroll
  for (int dd = 0; dd < DH; ++dd) { float df = acc[dd]-m2; vs += df*df; }
  vs += qdppf<0xB1>(vs);
  vs += qdppf<0x4E>(vs);
  float rs2 = rsqrtf(vs * (1.0f/DD) + 1e-5f);
  unsigned zq[4];
  #pragma unroll
  for (int j = 0; j < 4; ++j) {
    int d = hh*DH + 2*j;
    float za = (acc[2*j]  -m2)*rs2*g2[e*DD+d]   + bb2[e*DD+d];
    float zb = (acc[2*j+1]-m2)*rs2*g2[e*DD+d+1] + bb2[e*DD+d+1];
    zq[j] = pkh2(za, zb);
  }
  unsigned zp2[16];
  #pragma unroll
  for (int j = 0; j < 4; ++j) {
    zp2[j]    = qdpp<0x00>(zq[j]);
    zp2[4+j]  = qdpp<0x55>(zq[j]);
    zp2[8+j]  = qdpp<0xAA>(zq[j]);
    zp2[12+j] = qdpp<0xFF>(zq[j]);
  }

  // FFN1: f[hh*16 .. +16)
  float f[16];
  #pragma unroll
  for (int jj = 0; jj < 16; ++jj) {
    const uint4* row = (const uint4*)&wl[2048 + (e*64 + jj*4 + hh)*16];
    float a = b1[e*DFFN + hh*16 + jj];
    #pragma unroll
    for (int g4 = 0; g4 < 4; ++g4) {
      uint4 w4 = row[g4];
      a = fd2(zp2[4*g4+0], w4.x, a); a = fd2(zp2[4*g4+1], w4.y, a);
      a = fd2(zp2[4*g4+2], w4.z, a); a = fd2(zp2[4*g4+3], w4.w, a);
    }
    f[jj] = fmaxf(a, 0.0f);
  }
  // ---- f gather via DPP quad broadcast ----
  unsigned fq[8];
  #pragma unroll
  for (int j = 0; j < 8; ++j) fq[j] = pkh2(f[2*j], f[2*j+1]);
  unsigned fu[32];
  #pragma unroll
  for (int j = 0; j < 8; ++j) {
    fu[j]    = qdpp<0x00>(fq[j]);
    fu[8+j]  = qdpp<0x55>(fq[j]);
    fu[16+j] = qdpp<0xAA>(fq[j]);
    fu[24+j] = qdpp<0xFF>(fq[j]);
  }

  // FFN2 + residual + b2
  float acc2[DH];
  #pragma unroll
  for (int dd = 0; dd < DH; ++dd) {
    int d = hh*DH + dd;
    const int row16 = (e*32 + dd*4 + hh)*16;
    float a = acc[dd] + b2[e*DD + d];
    #pragma unroll
    for (int g4 = 0; g4 < 8; ++g4) {
      const int plane = (g4 >> 2);
      uint4 w4 = *(const uint4*)&wl[6144 + plane*2048 + row16 + 4*(g4 & 3)];
      a = fd2(fu[4*g4+0], w4.x, a); a = fd2(fu[4*g4+1], w4.y, a);
      a = fd2(fu[4*g4+2], w4.z, a); a = fd2(fu[4*g4+3], w4.w, a);
    }
    acc2[dd] = a;
  }
  float* op = out + ((size_t)((b*SS + s)*NCH + n))*DD + hh*DH;
  *(float4*)(op)     = make_float4(acc2[0], acc2[1], acc2[2], acc2[3]);
  *(float4*)(op + 4) = make_float4(acc2[4], acc2[5], acc2[6], acc2[7]);
}

// ---------------------------------------------------------------------------
extern "C" void kernel_launch(void* const* d_in, const int* in_sizes, int n_in,
                              void* d_out, int out_size, void* d_ws, size_t ws_size,
                              hipStream_t stream) {
  (void)in_sizes; (void)n_in; (void)out_size; (void)ws_size;
  const float* x   = (const float*)d_in[0];
  const float* ox  = (const float*)d_in[1];
  const float* sW  = (const float*)d_in[2];
  const float* sb  = (const float*)d_in[3];
  const float* Wq  = (const float*)d_in[4];
  const float* Wk  = (const float*)d_in[5];
  const float* Wv  = (const float*)d_in[6];
  const float* Wo  = (const float*)d_in[7];
  const float* g1  = (const float*)d_in[8];
  const float* b1n = (const float*)d_in[9];
  const float* g2  = (const float*)d_in[10];
  const float* b2n = (const float*)d_in[11];
  const float* W1  = (const float*)d_in[12];
  const float* bf1 = (const float*)d_in[13];
  const float* W2  = (const float*)d_in[14];
  const float* bf2 = (const float*)d_in[15];
  float* out = (float*)d_out;
  float* ws  = (float*)d_ws;

  decomp_prep_kernel<<<276, 1024, 0, stream>>>(x, ox, sb, g1, b1n,
                                               Wq, Wk, Wv, Wo, W1, W2, ws);
  fused_kernel<<<BB*NCH, 1024, 0, stream>>>(ws, g1, b1n, sW, sb, g2, b2n,
                                            bf1, bf2, out);
}